// Round 1
// baseline (1635.744 us; speedup 1.0000x reference)
//
#include <hip/hip_runtime.h>
#include <cstdint>

#define E 4096
#define SEQL 4096
#define NH 16
#define HD 256

typedef unsigned short u16;
typedef unsigned int u32;
typedef __attribute__((ext_vector_type(8))) short bf16x8;
typedef __attribute__((ext_vector_type(4))) float f32x4;

__device__ __forceinline__ u16 f2bf(float f) {
  union { float f; u32 u; } x; x.f = f;
  u32 r = x.u + 0x7FFFu + ((x.u >> 16) & 1u);
  return (u16)(r >> 16);
}
__device__ __forceinline__ float bf2f(u16 b) {
  union { u32 u; float f; } x; x.u = ((u32)b) << 16; return x.f;
}

__device__ __forceinline__ void gload_lds16(const void* g, void* l) {
  __builtin_amdgcn_global_load_lds((const __attribute__((address_space(1))) void*)g,
                                   (__attribute__((address_space(3))) void*)l, 16, 0, 0);
}

// ---------------- fp32 -> bf16 cast (vectorized) ----------------
__global__ __launch_bounds__(256) void cast_kernel(const float4* __restrict__ in,
                                                   ushort4* __restrict__ out, int n4) {
  int i = blockIdx.x * 256 + threadIdx.x;
  if (i < n4) {
    float4 v = in[i];
    ushort4 o;
    o.x = f2bf(v.x); o.y = f2bf(v.y); o.z = f2bf(v.z); o.w = f2bf(v.w);
    out[i] = o;
  }
}

// ---------------- sin/cos table: sc[s*32+p] = (sin, cos)(s * 10000^(-p/32)) ----------------
__global__ __launch_bounds__(256) void sincos_kernel(float2* __restrict__ sc) {
  int i = blockIdx.x * 256 + threadIdx.x;
  if (i < SEQL * 32) {
    int s = i >> 5, p = i & 31;
    float inv = powf(10000.0f, -(float)p * (1.0f / 32.0f));
    float a = (float)s * inv;
    sc[i] = make_float2(sinf(a), cosf(a));
  }
}

// ---------------- RoPE (GPT-J rotate-every-two) on first 64 dims of each head ----------------
__global__ __launch_bounds__(256) void rope_kernel(u16* __restrict__ q, u16* __restrict__ k,
                                                   const float2* __restrict__ sc) {
  int i = blockIdx.x * 256 + threadIdx.x;
  if (i >= SEQL * NH * 32) return;
  int p = i & 31, h = (i >> 5) & 15, s = i >> 9;
  float2 cs = sc[(s << 5) | p];   // x = sin, y = cos
  size_t off = ((size_t)s << 12) + ((size_t)h << 8) + ((size_t)p << 1);
  {
    u32* qp = (u32*)(q + off);
    u32 raw = *qp;
    float x0 = bf2f((u16)(raw & 0xFFFFu));
    float x1 = bf2f((u16)(raw >> 16));
    float o0 = x0 * cs.y - x1 * cs.x;
    float o1 = x1 * cs.y + x0 * cs.x;
    *qp = (u32)f2bf(o0) | ((u32)f2bf(o1) << 16);
  }
  {
    u32* kp = (u32*)(k + off);
    u32 raw = *kp;
    float x0 = bf2f((u16)(raw & 0xFFFFu));
    float x1 = bf2f((u16)(raw >> 16));
    float o0 = x0 * cs.y - x1 * cs.x;
    float o1 = x1 * cs.y + x0 * cs.x;
    *kp = (u32)f2bf(o0) | ((u32)f2bf(o1) << 16);
  }
}

// ---------------- bf16 GEMM, C[i][j] = sum_k A[i][k]*B[j][k]  (m97 structure + swizzle) ----------------
// 128x128 tile, BK=32, 256 threads (4 waves in 2x2 of 64x64), double-buffered LDS via global_load_lds.
// LDS chunk swizzle: physical chunk = logical ^ ((row>>1)&3); staged by pre-swizzling global src.
template <bool BF16OUT>
__global__ __launch_bounds__(256) void gemm_bt(const u16* __restrict__ A, const u16* __restrict__ B,
                                               void* __restrict__ Cp, int M, int N, int K) {
  __shared__ u16 As[2][128 * 32];
  __shared__ u16 Bs[2][128 * 32];
  const int tid = threadIdx.x, w = tid >> 6, lane = tid & 63;
  const int c15 = lane & 15, q4 = lane >> 4;

  // XCD-aware swizzle (grid is 1D, (M/128)*(N/128) blocks, divisible by 8)
  int bid = blockIdx.x;
  int cpx = gridDim.x >> 3;
  int sw = (bid & 7) * cpx + (bid >> 3);
  const int mt = M >> 7;
  const int bm = sw & (mt - 1), bn = sw / mt;
  const int row0 = bm << 7, col0 = bn << 7;
  const int wr = w >> 1, wc = w & 1;

  f32x4 acc[4][4] = {};

  auto stage = [&](int buf, int k0) {
#pragma unroll
    for (int i = 0; i < 2; ++i) {
      int p = w * 128 + i * 64 + lane;
      int r = p >> 2, cph = p & 3;
      int gl = cph ^ ((r >> 1) & 3);
      gload_lds16(A + (size_t)(row0 + r) * K + k0 + gl * 8, &As[buf][(w * 128 + i * 64) * 8]);
      gload_lds16(B + (size_t)(col0 + r) * K + k0 + gl * 8, &Bs[buf][(w * 128 + i * 64) * 8]);
    }
  };

  stage(0, 0);
  const int nt = K >> 5;
  for (int t = 0; t < nt; ++t) {
    const int cur = t & 1;
    __syncthreads();                      // drains prior stage (vmcnt) + protects buffer reuse
    if (t + 1 < nt) stage(cur ^ 1, (t + 1) << 5);
    bf16x8 af[4], bfr[4];
#pragma unroll
    for (int m = 0; m < 4; ++m) {
      int ra = wr * 64 + m * 16 + c15;
      int pga = q4 ^ ((ra >> 1) & 3);
      af[m] = *(const bf16x8*)&As[cur][ra * 32 + pga * 8];
      int rb = wc * 64 + m * 16 + c15;
      int pgb = q4 ^ ((rb >> 1) & 3);
      bfr[m] = *(const bf16x8*)&Bs[cur][rb * 32 + pgb * 8];
    }
#pragma unroll
    for (int m = 0; m < 4; ++m)
#pragma unroll
      for (int n = 0; n < 4; ++n)
        acc[m][n] = __builtin_amdgcn_mfma_f32_16x16x32_bf16(af[m], bfr[n], acc[m][n], 0, 0, 0);
  }

#pragma unroll
  for (int m = 0; m < 4; ++m) {
#pragma unroll
    for (int n = 0; n < 4; ++n) {
#pragma unroll
      for (int j = 0; j < 4; ++j) {
        int r = row0 + wr * 64 + m * 16 + q4 * 4 + j;
        int c = col0 + wc * 64 + n * 16 + c15;
        if constexpr (BF16OUT)
          ((u16*)Cp)[(size_t)r * N + c] = f2bf(acc[m][n][j]);
        else
          ((float*)Cp)[(size_t)r * N + c] = acc[m][n][j];
      }
    }
  }
}

// ---------------- causal flash attention, bf16 MFMA, online softmax ----------------
// grid (S/64 [reversed], NH), 256 threads (4 waves x 16 q-rows). KV tile = 64.
__global__ __launch_bounds__(256, 2) void attn_kernel(const u16* __restrict__ Q, const u16* __restrict__ Kt,
                                                      const u16* __restrict__ V, u16* __restrict__ O) {
  __shared__ u16 Ks[64 * 256];   // swizzled: row=key, 32 granules of 8; phys = logical ^ ((key&7)<<2)
  __shared__ u16 Vt[256 * 64];   // transposed+swizzled: row=d, 8 granules of 8; phys = logical ^ ((d>>1)&7)
  __shared__ u16 Ps[4][16 * 72]; // per-wave P buffer, pad 72 for conflict-free A-frag reads

  const int tid = threadIdx.x, w = tid >> 6, lane = tid & 63;
  const int c15 = lane & 15, q4 = lane >> 4;
  const int h = blockIdx.y;
  const int qt = (gridDim.x - 1) - blockIdx.x;   // big blocks first (LPT)
  const int qbase = qt * 64;

  // Q fragments (A operand): row = c15, k contiguous along d
  bf16x8 qf[8];
  {
    const u16* qp = Q + (size_t)(qbase + w * 16 + c15) * E + h * HD + q4 * 8;
#pragma unroll
    for (int kc = 0; kc < 8; ++kc) qf[kc] = *(const bf16x8*)(qp + kc * 32);
  }

  f32x4 oacc[16];
#pragma unroll
  for (int i = 0; i < 16; ++i) oacc[i] = f32x4{0.f, 0.f, 0.f, 0.f};
  float mrow[4] = {-3e38f, -3e38f, -3e38f, -3e38f};
  float lrow[4] = {0.f, 0.f, 0.f, 0.f};

  for (int t = 0; t <= qt; ++t) {
    const int kvbase = t * 64;
    __syncthreads();   // prior-iter LDS reads complete before restage

    // stage K tile via global_load_lds, pre-swizzled global source
#pragma unroll
    for (int i = 0; i < 8; ++i) {
      int p = (i * 4 + w) * 64 + lane;
      int r = p >> 5, pg = p & 31;
      int gl = pg ^ ((r & 7) << 2);
      gload_lds16(Kt + (size_t)(kvbase + r) * E + h * HD + gl * 8, &Ks[((i * 4 + w) * 64) * 8]);
    }
    // stage V transposed: lane = key (coalesced 16B rows), wave w covers d in [w*64, w*64+64)
#pragma unroll
    for (int i = 0; i < 8; ++i) {
      int d0 = w * 64 + i * 8;
      bf16x8 vv = *(const bf16x8*)(V + (size_t)(kvbase + lane) * E + h * HD + d0);
#pragma unroll
      for (int j = 0; j < 8; ++j) {
        int d = d0 + j;
        int pg = (lane >> 3) ^ ((d >> 1) & 7);
        Vt[d * 64 + pg * 8 + (lane & 7)] = (u16)vv[j];
      }
    }
    __syncthreads();

    // ---- QK^T : S[q16][key64] ----
    f32x4 sacc[4];
#pragma unroll
    for (int n = 0; n < 4; ++n) sacc[n] = f32x4{0.f, 0.f, 0.f, 0.f};
#pragma unroll
    for (int kk = 0; kk < 8; ++kk) {
#pragma unroll
      for (int n = 0; n < 4; ++n) {
        int key = n * 16 + c15;
        int pg5 = (kk * 4 + q4) ^ ((key & 7) << 2);
        bf16x8 kf = *(const bf16x8*)&Ks[key * 256 + pg5 * 8];
        sacc[n] = __builtin_amdgcn_mfma_f32_16x16x32_bf16(qf[kk], kf, sacc[n], 0, 0, 0);
      }
    }

    // ---- scale + causal mask (diagonal tile only) ----
    const bool diag = (t == qt);
#pragma unroll
    for (int n = 0; n < 4; ++n) {
#pragma unroll
      for (int j = 0; j < 4; ++j) {
        float s = sacc[n][j] * 0.0625f;
        if (diag) {
          int key = kvbase + n * 16 + c15;
          int qr = qbase + w * 16 + q4 * 4 + j;
          if (key > qr) s = -3e38f;
        }
        sacc[n][j] = s;
      }
    }

    // ---- online softmax (rows live in 16-lane groups) ----
    float rmax[4];
#pragma unroll
    for (int j = 0; j < 4; ++j)
      rmax[j] = fmaxf(fmaxf(sacc[0][j], sacc[1][j]), fmaxf(sacc[2][j], sacc[3][j]));
#pragma unroll
    for (int off = 1; off < 16; off <<= 1)
#pragma unroll
      for (int j = 0; j < 4; ++j) rmax[j] = fmaxf(rmax[j], __shfl_xor(rmax[j], off, 64));

    float mnew[4], scl[4], psum[4];
#pragma unroll
    for (int j = 0; j < 4; ++j) {
      mnew[j] = fmaxf(mrow[j], rmax[j]);
      scl[j] = __expf(mrow[j] - mnew[j]);
      mrow[j] = mnew[j];
      psum[j] = 0.f;
    }

    u16* Pw = &Ps[w][0];
#pragma unroll
    for (int n = 0; n < 4; ++n) {
#pragma unroll
      for (int j = 0; j < 4; ++j) {
        float p = __expf(sacc[n][j] - mnew[j]);
        psum[j] += p;
        Pw[(q4 * 4 + j) * 72 + n * 16 + c15] = f2bf(p);
      }
    }
#pragma unroll
    for (int off = 1; off < 16; off <<= 1)
#pragma unroll
      for (int j = 0; j < 4; ++j) psum[j] += __shfl_xor(psum[j], off, 64);
#pragma unroll
    for (int j = 0; j < 4; ++j) lrow[j] = lrow[j] * scl[j] + psum[j];
#pragma unroll
    for (int i = 0; i < 16; ++i)
#pragma unroll
      for (int j = 0; j < 4; ++j) oacc[i][j] *= scl[j];

    // wave-internal LDS write->read ordering
    asm volatile("s_waitcnt lgkmcnt(0)" ::: "memory");
    __builtin_amdgcn_sched_barrier(0);

    // ---- PV : O[q16][d256] += P[q16][key64] * V[key64][d256] ----
    bf16x8 pf[2];
#pragma unroll
    for (int kkp = 0; kkp < 2; ++kkp)
      pf[kkp] = *(const bf16x8*)(Pw + c15 * 72 + kkp * 32 + q4 * 8);
#pragma unroll
    for (int kkp = 0; kkp < 2; ++kkp) {
#pragma unroll
      for (int n = 0; n < 16; ++n) {
        int d = n * 16 + c15;
        int pg = (kkp * 4 + q4) ^ ((d >> 1) & 7);
        bf16x8 vf = *(const bf16x8*)&Vt[d * 64 + pg * 8];
        oacc[n] = __builtin_amdgcn_mfma_f32_16x16x32_bf16(pf[kkp], vf, oacc[n], 0, 0, 0);
      }
    }
  }

  // ---- finalize ----
#pragma unroll
  for (int n = 0; n < 16; ++n) {
#pragma unroll
    for (int j = 0; j < 4; ++j) {
      int r = qbase + w * 16 + q4 * 4 + j;
      int c = h * HD + n * 16 + c15;
      O[(size_t)r * E + c] = f2bf(oacc[n][j] / lrow[j]);
    }
  }
}

// ---------------- launch ----------------
extern "C" void kernel_launch(void* const* d_in, const int* in_sizes, int n_in,
                              void* d_out, int out_size, void* d_ws, size_t ws_size,
                              hipStream_t stream) {
  const float* hs = (const float*)d_in[0];
  const float* wq = (const float*)d_in[1];
  const float* wk = (const float*)d_in[2];
  const float* wv = (const float*)d_in[3];
  const float* wo = (const float*)d_in[4];
  float* out = (float*)d_out;

  const size_t SZ = (size_t)SEQL * E;
  const size_t SZb = SZ * 2;
  char* ws = (char*)d_ws;
  u16* hs_bf = (u16*)(ws);
  u16* wbuf  = (u16*)(ws + SZb);
  u16* q_bf  = (u16*)(ws + 2 * SZb);
  u16* k_bf  = (u16*)(ws + 3 * SZb);
  u16* v_bf  = (u16*)(ws + 4 * SZb);
  u16* ao_bf = (u16*)(ws + 5 * SZb);
  float2* sc = (float2*)(ws + 6 * SZb);

  const int n4 = (int)(SZ / 4);
  const int cblocks = (n4 + 255) / 256;

  cast_kernel<<<cblocks, 256, 0, stream>>>((const float4*)hs, (ushort4*)hs_bf, n4);
  sincos_kernel<<<(SEQL * 32 + 255) / 256, 256, 0, stream>>>(sc);

  // Q = hs @ wq^T
  cast_kernel<<<cblocks, 256, 0, stream>>>((const float4*)wq, (ushort4*)wbuf, n4);
  gemm_bt<true><<<1024, 256, 0, stream>>>(hs_bf, wbuf, q_bf, 4096, 4096, 4096);
  // K = hs @ wk^T
  cast_kernel<<<cblocks, 256, 0, stream>>>((const float4*)wk, (ushort4*)wbuf, n4);
  gemm_bt<true><<<1024, 256, 0, stream>>>(hs_bf, wbuf, k_bf, 4096, 4096, 4096);
  // V = hs @ wv^T
  cast_kernel<<<cblocks, 256, 0, stream>>>((const float4*)wv, (ushort4*)wbuf, n4);
  gemm_bt<true><<<1024, 256, 0, stream>>>(hs_bf, wbuf, v_bf, 4096, 4096, 4096);

  // RoPE on q, k
  rope_kernel<<<(SEQL * NH * 32 + 255) / 256, 256, 0, stream>>>(q_bf, k_bf, sc);

  // attention
  attn_kernel<<<dim3(64, 16), 256, 0, stream>>>(q_bf, k_bf, v_bf, ao_bf);

  // out = attn_out @ wo^T (fp32 epilogue)
  cast_kernel<<<cblocks, 256, 0, stream>>>((const float4*)wo, (ushort4*)wbuf, n4);
  gemm_bt<false><<<1024, 256, 0, stream>>>(ao_bf, wbuf, out, 4096, 4096, 4096);
}